// Round 4
// baseline (359.215 us; speedup 1.0000x reference)
//
#include <hip/hip_runtime.h>
#include <hip/hip_bf16.h>

typedef __bf16 bf16x8 __attribute__((ext_vector_type(8)));
typedef __bf16 bf16x4 __attribute__((ext_vector_type(4)));
typedef float floatx4 __attribute__((ext_vector_type(4)));
typedef float floatx4u __attribute__((ext_vector_type(4), aligned(4)));

#define ROWK 200   // zt row stride in bf16 elements (192 + 8 pad)
#define ZROWS 100  // LDS = 100*200*2 = 40000 B <= 40960 -> 4 blocks/CU

// ---------------- prep: Wp (bf16 A-operand), effAB (bf16 B-operand), bias2T[w*128+c] ----------------
__global__ void sgc_prep(const float* __restrict__ W, const float* __restrict__ b,
                         const float* __restrict__ A, const float* __restrict__ edge,
                         const float* __restrict__ adA,
                         __hip_bfloat16* __restrict__ Wp, __hip_bfloat16* __restrict__ effAB,
                         float* __restrict__ bias2T) {
  int tid = blockIdx.x * blockDim.x + threadIdx.x;
  int nthr = gridDim.x * blockDim.x;
  for (int i = tid; i < 24576; i += nthr) {
    int c = i / 192; int r = i - c * 192; int k = r >> 6; int ci = r & 63;
    Wp[i] = __float2bfloat16(W[(k * 128 + c) * 64 + ci]);
  }
  for (int i = tid; i < 2560; i += nthr) {
    int n = i >> 5; int v = i & 31;
    float val = 0.f;
    if (n < 75 && v < 25) {
      int k = n / 25; int w = n - k * 25;
      int idx = (k * 25 + v) * 25 + w;
      val = A[idx] * edge[idx] + adA[idx];
    }
    effAB[i] = __float2bfloat16(val);
  }
  for (int i = tid; i < 3200; i += nthr) {
    int w = i >> 7; int c = i & 127;
    float s = 0.f;
    for (int k = 0; k < 3; k++) {
      float sv = 0.f;
      for (int v = 0; v < 25; v++) {
        int idx = (k * 25 + v) * 25 + w;
        sv += A[idx] * edge[idx] + adA[idx];
      }
      s += b[k * 128 + c] * sv;
    }
    bias2T[i] = s;
  }
}

// ---------------- main fused kernel: 4 pixels/block; store-overlapped epilogue ----------------
__global__ __launch_bounds__(256, 4)
void sgc_main(const float* __restrict__ x,
              const __hip_bfloat16* __restrict__ Wp,
              const __hip_bfloat16* __restrict__ effAB,
              const float* __restrict__ bias2T,
              float* __restrict__ out) {
  __shared__ __hip_bfloat16 lds[ZROWS * ROWK];   // 40000 B
  __hip_bfloat16* zt = lds;                      // stage-B B-operand tile (100 rows x 400 B)
  float* xs = (float*)lds;                       // x staging: [(tt*64+ci)*28 + v]
  float* eb = (float*)lds;                       // epilogue: 64 slots x 100 f32 = bytes 0..25599 = zt rows 0..63

  const int tid = threadIdx.x;
  const int lane = tid & 63;
  const int wv = tid >> 6;
  const int blk0 = blockIdx.x;
  const int blk = (blk0 & 7) * 512 + (blk0 >> 3);   // XCD-bijective swizzle (4096 % 8 == 0)
  const int col = lane & 15;
  const int quad = lane >> 4;
  const int kb = quad * 8;
  const int g0 = blk * 4;
  const int n = g0 >> 8, t0 = g0 & 255;

  // ---- coalesced x load -> regs ----
  floatx4 xr[7];
  const float* xn = x + (size_t)n * 64 * 6400 + t0 * 25;
#pragma unroll
  for (int i = 0; i < 7; i++) {
    int f = tid + 256 * i;
    if (f < 1600) {
      int ci = f / 25, q = f - ci * 25;
      xr[i] = *(const floatx4u*)(xn + (size_t)ci * 6400 + q * 4);
    }
  }

  // ---- effA B-fragments ----
  bf16x8 bA[5];
#pragma unroll
  for (int nt = 0; nt < 5; nt++)
    bA[nt] = *(const bf16x8*)(effAB + (nt * 16 + col) * 32 + kb);

  // ---- acc pass-1 init from bias2T (nt 0..3) ----
  floatx4 accA[2][4];
#pragma unroll
  for (int nt = 0; nt < 4; nt++) {
    int nn = nt * 16 + col;
    int p = (nn * 41) >> 10;
    int w = nn - p * 25;
#pragma unroll
    for (int mtl = 0; mtl < 2; mtl++) {
      int c0 = (2 * wv + mtl) * 16 + quad * 4;
      accA[mtl][nt] = *(const floatx4*)(bias2T + w * 128 + c0);
    }
  }

  // ---- scatter x regs -> LDS xs ----
#pragma unroll
  for (int i = 0; i < 7; i++) {
    int f = tid + 256 * i;
    if (f < 1600) {
      int ci = f / 25;
      int q4 = (f - ci * 25) * 4;
#pragma unroll
      for (int e = 0; e < 4; e++) {
        int rr = q4 + e;
        int tt = rr / 25, v = rr - tt * 25;
        xs[(tt * 64 + ci) * 28 + v] = xr[i][e];
      }
    }
  }

  __syncthreads();   // xs ready

  // ---- stage-A A-fragments from LDS ----
  bf16x8 xa[4];
#pragma unroll
  for (int mt = 0; mt < 4; mt++) {
    int ci = mt * 16 + col;
    const float* base = xs + (wv * 64 + ci) * 28;
    if (quad < 3) {
      floatx4 a = *(const floatx4*)(base + kb);
      floatx4 c = *(const floatx4*)(base + kb + 4);
      xa[mt] = (bf16x8){(__bf16)a.x, (__bf16)a.y, (__bf16)a.z, (__bf16)a.w,
                        (__bf16)c.x, (__bf16)c.y, (__bf16)c.z, (__bf16)c.w};
    } else {
      float v24 = base[24];
      xa[mt] = (bf16x8){(__bf16)v24, (__bf16)0.f, (__bf16)0.f, (__bf16)0.f,
                        (__bf16)0.f, (__bf16)0.f, (__bf16)0.f, (__bf16)0.f};
    }
  }

  __syncthreads();   // frags read; zt may overwrite xs

  // ---- stage A MFMA + zt writes ----
#pragma unroll
  for (int mt = 0; mt < 4; mt++) {
    floatx4 zacc[5];
#pragma unroll
    for (int nt = 0; nt < 5; nt++) {
      zacc[nt] = (floatx4){0.f, 0.f, 0.f, 0.f};
      zacc[nt] = __builtin_amdgcn_mfma_f32_16x16x32_bf16(xa[mt], bA[nt], zacc[nt], 0, 0, 0);
    }
#pragma unroll
    for (int nt = 0; nt < 5; nt++) {
      int nn = nt * 16 + col;
      if (nn < 75) {
        int k = (nn * 41) >> 10;
        int w = nn - k * 25;
        bf16x4 zb = (bf16x4){(__bf16)zacc[nt][0], (__bf16)zacc[nt][1],
                             (__bf16)zacc[nt][2], (__bf16)zacc[nt][3]};
        *(bf16x4*)(zt + (wv * 25 + w) * ROWK + k * 64 + mt * 16 + quad * 4) = zb;
      }
    }
  }

  // ---- W' A-fragments preload ----
  bf16x8 afr[2][6];
#pragma unroll
  for (int mtl = 0; mtl < 2; mtl++) {
    int c = (2 * wv + mtl) * 16 + col;
    const __hip_bfloat16* wrow = Wp + c * 192;
#pragma unroll
    for (int ks = 0; ks < 6; ks++)
      afr[mtl][ks] = *(const bf16x8*)(wrow + ks * 32 + kb);
  }

  __syncthreads();   // zt ready

  // ---- stage B pass 1: nt 0..3 (zt rows 0..63) ----
#pragma unroll
  for (int ks = 0; ks < 6; ks++) {
    bf16x8 bfr[4];
#pragma unroll
    for (int nt = 0; nt < 4; nt++)
      bfr[nt] = *(const bf16x8*)(zt + (nt * 16 + col) * ROWK + ks * 32 + kb);
#pragma unroll
    for (int nt = 0; nt < 4; nt++) {
      accA[0][nt] = __builtin_amdgcn_mfma_f32_16x16x32_bf16(afr[0][ks], bfr[nt], accA[0][nt], 0, 0, 0);
      accA[1][nt] = __builtin_amdgcn_mfma_f32_16x16x32_bf16(afr[1][ks], bfr[nt], accA[1][nt], 0, 0, 0);
    }
  }

  __syncthreads();   // zt rows 0..63 dead -> eb may reuse

  // ---- stage h0 cols 0..63 (pass-1 mtl=0) ----
  {
    int slotbase = wv * 16 + quad * 4;
#pragma unroll
    for (int nt = 0; nt < 4; nt++) {
      int nn = nt * 16 + col;
#pragma unroll
      for (int r = 0; r < 4; r++)
        eb[(slotbase + r) * 100 + nn] = accA[0][nt][r];
    }
  }

  __syncthreads();   // eb h0 cols 0..63 published

  // ---- EARLY h0 stores (cols 0..63): issue now, drain under pass-2 MFMA ----
#pragma unroll
  for (int j = 0; j < 4; j++) {
    int item = tid + 256 * j;          // 0..1023, no predicate needed
    int slot = item >> 4, q = item & 15;
    floatx4 v = *(const floatx4*)(eb + slot * 100 + q * 4);
    int c = 32 * (slot >> 4) + (slot & 15);   // h=0
    float* ob = out + ((size_t)(n * 128 + c) * 256 + t0) * 25 + q * 4;
    *(floatx4u*)ob = v;
  }

  // ---- acc pass-2 init from bias2T (nt 4..6) — loads overlap in-flight stores ----
  floatx4 accB[2][3];
#pragma unroll
  for (int nt = 0; nt < 3; nt++) {
    int nn = (nt + 4) * 16 + col;
    int p = (nn * 41) >> 10;
    int w = nn - p * 25;
#pragma unroll
    for (int mtl = 0; mtl < 2; mtl++) {
      int c0 = (2 * wv + mtl) * 16 + quad * 4;
      accB[mtl][nt] = *(const floatx4*)(bias2T + w * 128 + c0);
    }
  }

  // ---- stage B pass 2: nt 4..6 (zt rows 64..99 — untouched by eb) ----
  int zoffB[3];
#pragma unroll
  for (int nt = 0; nt < 3; nt++) {
    int nn = (nt + 4) * 16 + col;
    int rr = (nt == 2) ? (nn < 100 ? nn : 99) : nn;
    zoffB[nt] = rr * ROWK + kb;
  }
#pragma unroll
  for (int ks = 0; ks < 6; ks++) {
    bf16x8 bfr[3];
#pragma unroll
    for (int nt = 0; nt < 3; nt++)
      bfr[nt] = *(const bf16x8*)(zt + zoffB[nt] + ks * 32);
#pragma unroll
    for (int nt = 0; nt < 3; nt++) {
      accB[0][nt] = __builtin_amdgcn_mfma_f32_16x16x32_bf16(afr[0][ks], bfr[nt], accB[0][nt], 0, 0, 0);
      accB[1][nt] = __builtin_amdgcn_mfma_f32_16x16x32_bf16(afr[1][ks], bfr[nt], accB[1][nt], 0, 0, 0);
    }
  }

  // ---- stage h0 cols 64..99 (disjoint from cols 0..63 other waves may still be reading) ----
  {
    int slotbase = wv * 16 + quad * 4;
#pragma unroll
    for (int nt = 0; nt < 3; nt++) {
      int nn = (nt + 4) * 16 + col;
      if (nn < 100) {
#pragma unroll
        for (int r = 0; r < 4; r++)
          eb[(slotbase + r) * 100 + nn] = accB[0][nt][r];
      }
    }
  }

  __syncthreads();   // h0 cols 64..99 published; all early-store eb reads complete

  // ---- h0 tail stores (q = 16..24 -> cols 64..99) ----
#pragma unroll
  for (int j = 0; j < 3; j++) {
    int item = tid + 256 * j;
    if (item < 576) {
      int slot = item / 9;
      int q = 16 + (item - slot * 9);
      floatx4 v = *(const floatx4*)(eb + slot * 100 + q * 4);
      int c = 32 * (slot >> 4) + (slot & 15);   // h=0
      float* ob = out + ((size_t)(n * 128 + c) * 256 + t0) * 25 + q * 4;
      *(floatx4u*)ob = v;
    }
  }

  __syncthreads();   // h0 tail eb reads done -> h1 may overwrite eb

  // ---- stage h1 (mtl=1, both passes) ----
  {
    int slotbase = wv * 16 + quad * 4;
#pragma unroll
    for (int nt = 0; nt < 4; nt++) {
      int nn = nt * 16 + col;
#pragma unroll
      for (int r = 0; r < 4; r++)
        eb[(slotbase + r) * 100 + nn] = accA[1][nt][r];
    }
#pragma unroll
    for (int nt = 0; nt < 3; nt++) {
      int nn = (nt + 4) * 16 + col;
      if (nn < 100) {
#pragma unroll
        for (int r = 0; r < 4; r++)
          eb[(slotbase + r) * 100 + nn] = accB[1][nt][r];
      }
    }
  }

  __syncthreads();   // eb h1 complete

  // ---- coalesced store h1 ----
#pragma unroll
  for (int i = 0; i < 7; i++) {
    int f = tid + 256 * i;
    if (f < 1600) {
      int slot = f / 25, q = f - slot * 25;
      floatx4 v = *(const floatx4*)(eb + slot * 100 + q * 4);
      int c = 32 * (slot >> 4) + 16 + (slot & 15);   // h=1
      float* ob = out + ((size_t)(n * 128 + c) * 256 + t0) * 25 + q * 4;
      *(floatx4u*)ob = v;
    }
  }
}

extern "C" void kernel_launch(void* const* d_in, const int* in_sizes, int n_in,
                              void* d_out, int out_size, void* d_ws, size_t ws_size,
                              hipStream_t stream) {
  const float* x    = (const float*)d_in[0];
  const float* W    = (const float*)d_in[1];
  const float* b    = (const float*)d_in[2];
  const float* A    = (const float*)d_in[3];
  const float* edge = (const float*)d_in[4];
  const float* adA  = (const float*)d_in[5];
  float* out = (float*)d_out;

  char* ws = (char*)d_ws;
  __hip_bfloat16* Wp    = (__hip_bfloat16*)ws;           // 49152 B
  __hip_bfloat16* effAB = (__hip_bfloat16*)(ws + 49152); // 5120 B
  float* bias2T         = (float*)(ws + 54272);          // 12800 B

  sgc_prep<<<64, 256, 0, stream>>>(W, b, A, edge, adA, Wp, effAB, bias2T);
  sgc_main<<<4096, 256, 0, stream>>>(x, Wp, effAB, bias2T, out);
}

// Round 5
// 346.110 us; speedup vs baseline: 1.0379x; 1.0379x over previous
//
#include <hip/hip_runtime.h>
#include <hip/hip_bf16.h>

typedef __bf16 bf16x8 __attribute__((ext_vector_type(8)));
typedef __bf16 bf16x4 __attribute__((ext_vector_type(4)));
typedef float floatx4 __attribute__((ext_vector_type(4)));
typedef float floatx4u __attribute__((ext_vector_type(4), aligned(4)));

#define ROWK 200   // zt row stride in bf16 elements (192 + 8 pad)
#define ZROWS 100  // LDS = 100*200*2 = 40000 B <= 40960 -> 4 blocks/CU

// ---------------- prep: Wp (bf16 A-operand), effAB (bf16 B-operand), bias2T[w*128+c] ----------------
__global__ void sgc_prep(const float* __restrict__ W, const float* __restrict__ b,
                         const float* __restrict__ A, const float* __restrict__ edge,
                         const float* __restrict__ adA,
                         __hip_bfloat16* __restrict__ Wp, __hip_bfloat16* __restrict__ effAB,
                         float* __restrict__ bias2T) {
  int tid = blockIdx.x * blockDim.x + threadIdx.x;
  int nthr = gridDim.x * blockDim.x;
  for (int i = tid; i < 24576; i += nthr) {
    int c = i / 192; int r = i - c * 192; int k = r >> 6; int ci = r & 63;
    Wp[i] = __float2bfloat16(W[(k * 128 + c) * 64 + ci]);
  }
  for (int i = tid; i < 2560; i += nthr) {
    int n = i >> 5; int v = i & 31;
    float val = 0.f;
    if (n < 75 && v < 25) {
      int k = n / 25; int w = n - k * 25;
      int idx = (k * 25 + v) * 25 + w;
      val = A[idx] * edge[idx] + adA[idx];
    }
    effAB[i] = __float2bfloat16(val);
  }
  for (int i = tid; i < 3200; i += nthr) {
    int w = i >> 7; int c = i & 127;
    float s = 0.f;
    for (int k = 0; k < 3; k++) {
      float sv = 0.f;
      for (int v = 0; v < 25; v++) {
        int idx = (k * 25 + v) * 25 + w;
        sv += A[idx] * edge[idx] + adA[idx];
      }
      s += b[k * 128 + c] * sv;
    }
    bias2T[i] = s;
  }
}

// ---------------- main fused kernel: 4 pixels/block; N-split stage B for 4 blocks/CU ----------------
__global__ __launch_bounds__(256, 4)
void sgc_main(const float* __restrict__ x,
              const __hip_bfloat16* __restrict__ Wp,
              const __hip_bfloat16* __restrict__ effAB,
              const float* __restrict__ bias2T,
              float* __restrict__ out) {
  __shared__ __hip_bfloat16 lds[ZROWS * ROWK];   // 40000 B
  __hip_bfloat16* zt = lds;                      // stage-B B-operand tile (100 rows x 400 B)
  float* xs = (float*)lds;                       // x staging: [(tt*64+ci)*28 + v] (28656 B)
  float* eb = (float*)lds;                       // epilogue: 64 slots x 100 = 25600 B (= zt rows 0..63)

  const int tid = threadIdx.x;
  const int lane = tid & 63;
  const int wv = tid >> 6;
  // XCD-bijective swizzle: 4096 blocks, 8 XCDs -> contiguous 512-block chunks per XCD
  const int blk0 = blockIdx.x;
  const int blk = (blk0 & 7) * 512 + (blk0 >> 3);
  const int col = lane & 15;
  const int quad = lane >> 4;
  const int kb = quad * 8;
  const int g0 = blk * 4;
  const int n = g0 >> 8, t0 = g0 & 255;          // 4 consecutive t, same n

  // ---- coalesced x load -> regs (64 rows x 400B contiguous chunks) ----
  floatx4 xr[7];
  const float* xn = x + (size_t)n * 64 * 6400 + t0 * 25;
#pragma unroll
  for (int i = 0; i < 7; i++) {
    int f = tid + 256 * i;
    if (f < 1600) {
      int ci = f / 25, q = f - ci * 25;
      xr[i] = *(const floatx4u*)(xn + (size_t)ci * 6400 + q * 4);
    }
  }

  // ---- effA B-fragments ----
  bf16x8 bA[5];
#pragma unroll
  for (int nt = 0; nt < 5; nt++)
    bA[nt] = *(const bf16x8*)(effAB + (nt * 16 + col) * 32 + kb);

  // ---- acc pass-1 init from bias2T (nt 0..3) ----
  floatx4 accA[2][4];
#pragma unroll
  for (int nt = 0; nt < 4; nt++) {
    int nn = nt * 16 + col;
    int p = (nn * 41) >> 10;
    int w = nn - p * 25;
#pragma unroll
    for (int mtl = 0; mtl < 2; mtl++) {
      int c0 = (2 * wv + mtl) * 16 + quad * 4;
      accA[mtl][nt] = *(const floatx4*)(bias2T + w * 128 + c0);
    }
  }

  // ---- scatter x regs -> LDS xs[(tt*64+ci)*28 + v] ----
#pragma unroll
  for (int i = 0; i < 7; i++) {
    int f = tid + 256 * i;
    if (f < 1600) {
      int ci = f / 25;
      int q4 = (f - ci * 25) * 4;
#pragma unroll
      for (int e = 0; e < 4; e++) {
        int rr = q4 + e;                          // 0..99 = tt*25 + v
        int tt = rr / 25, v = rr - tt * 25;
        xs[(tt * 64 + ci) * 28 + v] = xr[i][e];
      }
    }
  }

  __syncthreads();   // xs ready

  // ---- stage-A A-fragments from LDS ----
  bf16x8 xa[4];
#pragma unroll
  for (int mt = 0; mt < 4; mt++) {
    int ci = mt * 16 + col;
    const float* base = xs + (wv * 64 + ci) * 28;
    if (quad < 3) {
      floatx4 a = *(const floatx4*)(base + kb);
      floatx4 c = *(const floatx4*)(base + kb + 4);
      xa[mt] = (bf16x8){(__bf16)a.x, (__bf16)a.y, (__bf16)a.z, (__bf16)a.w,
                        (__bf16)c.x, (__bf16)c.y, (__bf16)c.z, (__bf16)c.w};
    } else {
      float v24 = base[24];
      xa[mt] = (bf16x8){(__bf16)v24, (__bf16)0.f, (__bf16)0.f, (__bf16)0.f,
                        (__bf16)0.f, (__bf16)0.f, (__bf16)0.f, (__bf16)0.f};
    }
  }

  __syncthreads();   // all frags read; zt may overwrite xs space

  // ---- stage A MFMA + zt writes ----
#pragma unroll
  for (int mt = 0; mt < 4; mt++) {
    floatx4 zacc[5];
#pragma unroll
    for (int nt = 0; nt < 5; nt++) {
      zacc[nt] = (floatx4){0.f, 0.f, 0.f, 0.f};
      zacc[nt] = __builtin_amdgcn_mfma_f32_16x16x32_bf16(xa[mt], bA[nt], zacc[nt], 0, 0, 0);
    }
#pragma unroll
    for (int nt = 0; nt < 5; nt++) {
      int nn = nt * 16 + col;
      if (nn < 75) {
        int k = (nn * 41) >> 10;
        int w = nn - k * 25;
        bf16x4 zb = (bf16x4){(__bf16)zacc[nt][0], (__bf16)zacc[nt][1],
                             (__bf16)zacc[nt][2], (__bf16)zacc[nt][3]};
        *(bf16x4*)(zt + (wv * 25 + w) * ROWK + k * 64 + mt * 16 + quad * 4) = zb;
      }
    }
  }

  // ---- W' A-fragments preload (after stage A so stage-A register peak stays low) ----
  bf16x8 afr[2][6];
#pragma unroll
  for (int mtl = 0; mtl < 2; mtl++) {
    int c = (2 * wv + mtl) * 16 + col;
    const __hip_bfloat16* wrow = Wp + c * 192;
#pragma unroll
    for (int ks = 0; ks < 6; ks++)
      afr[mtl][ks] = *(const bf16x8*)(wrow + ks * 32 + kb);
  }

  __syncthreads();   // zt ready

  // ---- stage B pass 1: nt 0..3 (zt rows 0..63) ----
#pragma unroll
  for (int ks = 0; ks < 6; ks++) {
    bf16x8 bfr[4];
#pragma unroll
    for (int nt = 0; nt < 4; nt++)
      bfr[nt] = *(const bf16x8*)(zt + (nt * 16 + col) * ROWK + ks * 32 + kb);
#pragma unroll
    for (int nt = 0; nt < 4; nt++) {
      accA[0][nt] = __builtin_amdgcn_mfma_f32_16x16x32_bf16(afr[0][ks], bfr[nt], accA[0][nt], 0, 0, 0);
      accA[1][nt] = __builtin_amdgcn_mfma_f32_16x16x32_bf16(afr[1][ks], bfr[nt], accA[1][nt], 0, 0, 0);
    }
  }

  __syncthreads();   // all waves done with zt rows 0..63 -> eb may reuse them

  // ---- stage h=0 pass-1 results into eb (overlaps with pass 2) ----
  {
    int slotbase = wv * 16 + quad * 4;
#pragma unroll
    for (int nt = 0; nt < 4; nt++) {
      int nn = nt * 16 + col;
#pragma unroll
      for (int r = 0; r < 4; r++)
        eb[(slotbase + r) * 100 + nn] = accA[0][nt][r];
    }
  }

  // ---- acc pass-2 init from bias2T (nt 4..6) ----
  floatx4 accB[2][3];
#pragma unroll
  for (int nt = 0; nt < 3; nt++) {
    int nn = (nt + 4) * 16 + col;
    int p = (nn * 41) >> 10;
    int w = nn - p * 25;                          // nn in [100,112): w in [0,12), in-bounds
#pragma unroll
    for (int mtl = 0; mtl < 2; mtl++) {
      int c0 = (2 * wv + mtl) * 16 + quad * 4;
      accB[mtl][nt] = *(const floatx4*)(bias2T + w * 128 + c0);
    }
  }

  // ---- stage B pass 2: nt 4..6 (zt rows 64..99; clamp discarded cols nn>=100) ----
  int zoffB[3];
#pragma unroll
  for (int nt = 0; nt < 3; nt++) {
    int nn = (nt + 4) * 16 + col;
    int rr = (nt == 2) ? (nn < 100 ? nn : 99) : nn;
    zoffB[nt] = rr * ROWK + kb;
  }
#pragma unroll
  for (int ks = 0; ks < 6; ks++) {
    bf16x8 bfr[3];
#pragma unroll
    for (int nt = 0; nt < 3; nt++)
      bfr[nt] = *(const bf16x8*)(zt + zoffB[nt] + ks * 32);
#pragma unroll
    for (int nt = 0; nt < 3; nt++) {
      accB[0][nt] = __builtin_amdgcn_mfma_f32_16x16x32_bf16(afr[0][ks], bfr[nt], accB[0][nt], 0, 0, 0);
      accB[1][nt] = __builtin_amdgcn_mfma_f32_16x16x32_bf16(afr[1][ks], bfr[nt], accB[1][nt], 0, 0, 0);
    }
  }

  // ---- stage h=0 pass-2 results into eb ----
  {
    int slotbase = wv * 16 + quad * 4;
#pragma unroll
    for (int nt = 0; nt < 3; nt++) {
      int nn = (nt + 4) * 16 + col;
      if (nn < 100) {
#pragma unroll
        for (int r = 0; r < 4; r++)
          eb[(slotbase + r) * 100 + nn] = accB[0][nt][r];
      }
    }
  }

  __syncthreads();   // eb h=0 complete

  // ---- coalesced store h=0 ----
#pragma unroll
  for (int i = 0; i < 7; i++) {
    int f = tid + 256 * i;
    if (f < 1600) {
      int slot = f / 25, q = f - slot * 25;
      floatx4 v = *(const floatx4*)(eb + slot * 100 + q * 4);
      int c = 32 * (slot >> 4) + (slot & 15);   // h=0
      float* ob = out + ((size_t)(n * 128 + c) * 256 + t0) * 25 + q * 4;
      *(floatx4u*)ob = v;
    }
  }

  __syncthreads();   // h=0 drained

  // ---- stage h=1 into eb ----
  {
    int slotbase = wv * 16 + quad * 4;
#pragma unroll
    for (int nt = 0; nt < 4; nt++) {
      int nn = nt * 16 + col;
#pragma unroll
      for (int r = 0; r < 4; r++)
        eb[(slotbase + r) * 100 + nn] = accA[1][nt][r];
    }
#pragma unroll
    for (int nt = 0; nt < 3; nt++) {
      int nn = (nt + 4) * 16 + col;
      if (nn < 100) {
#pragma unroll
        for (int r = 0; r < 4; r++)
          eb[(slotbase + r) * 100 + nn] = accB[1][nt][r];
      }
    }
  }

  __syncthreads();   // eb h=1 complete

  // ---- coalesced store h=1 ----
#pragma unroll
  for (int i = 0; i < 7; i++) {
    int f = tid + 256 * i;
    if (f < 1600) {
      int slot = f / 25, q = f - slot * 25;
      floatx4 v = *(const floatx4*)(eb + slot * 100 + q * 4);
      int c = 32 * (slot >> 4) + 16 + (slot & 15);   // h=1
      float* ob = out + ((size_t)(n * 128 + c) * 256 + t0) * 25 + q * 4;
      *(floatx4u*)ob = v;
    }
  }
}

extern "C" void kernel_launch(void* const* d_in, const int* in_sizes, int n_in,
                              void* d_out, int out_size, void* d_ws, size_t ws_size,
                              hipStream_t stream) {
  const float* x    = (const float*)d_in[0];
  const float* W    = (const float*)d_in[1];
  const float* b    = (const float*)d_in[2];
  const float* A    = (const float*)d_in[3];
  const float* edge = (const float*)d_in[4];
  const float* adA  = (const float*)d_in[5];
  float* out = (float*)d_out;

  char* ws = (char*)d_ws;
  __hip_bfloat16* Wp    = (__hip_bfloat16*)ws;           // 49152 B
  __hip_bfloat16* effAB = (__hip_bfloat16*)(ws + 49152); // 5120 B
  float* bias2T         = (float*)(ws + 54272);          // 12800 B

  sgc_prep<<<64, 256, 0, stream>>>(W, b, A, edge, adA, Wp, effAB, bias2T);
  sgc_main<<<4096, 256, 0, stream>>>(x, Wp, effAB, bias2T, out);
}